// Round 7
// baseline (209.028 us; speedup 1.0000x reference)
//
#include <hip/hip_runtime.h>
#include <math.h>

#define Bv 4
#define Nv 256
#define Cv 32
#define Mv 4
#define OUTv 64
#define MCv (Mv*Cv)      // 128
#define ITILE 4

typedef _Float16 h8 __attribute__((ext_vector_type(8)));
typedef _Float16 h4 __attribute__((ext_vector_type(4)));
typedef float f4 __attribute__((ext_vector_type(4)));

// ---- static device scratch ----
__device__ __align__(16) float g_rs  [Bv * Nv * Cv];
__device__ __align__(16) float g_cs  [Bv * Nv * Cv];
__device__ __align__(16) float g_dgx [Bv * Nv * Cv];
__device__ __align__(16) float g_nb  [Bv * Nv * Mv];
__device__ __align__(16) float g_S1  [Bv * Nv * MCv];
__device__ __align__(16) float g_S2  [Bv * Nv * MCv];
__device__ __align__(16) float g_obj0[Bv * 64];         // atomic: [rcs(32), ds(32)]
__device__ __align__(16) float g_rcs2[Bv * MCv];        // atomic accum
__device__ __align__(16) float g_ds2 [Bv * MCv];        // atomic accum
__device__ __align__(16) float g_addv[Bv * Nv * OUTv];
__device__ __align__(16) _Float16 g_wfrag[8 * 4 * 64 * 8];   // 32 KB

// ---------------- K0: pack w2d -> f16 fragment order + zero accumulators ------
__global__ void k_wpackz(const float* __restrict__ w2d) {
    int t = threadIdx.x;
    int r = blockIdx.x;
    if (r == 8) {   // zero atomic accumulators
        if (t < 128) ((float4*)g_rcs2)[t] = {0.f,0.f,0.f,0.f};
        else         ((float4*)g_ds2)[t - 128] = {0.f,0.f,0.f,0.f};
        if (t < 64)  ((float4*)g_obj0)[t] = {0.f,0.f,0.f,0.f};
        return;
    }
    int fi = r * 256 + t;
    int s = fi >> 8, q = (fi >> 6) & 3, lane = fi & 63;
    int k0 = s * 32 + ((lane >> 4) << 3);
    int o = q * 16 + (lane & 15);
    #pragma unroll
    for (int jj = 0; jj < 8; jj++)
        g_wfrag[fi * 8 + jj] = (_Float16)w2d[(size_t)(k0 + jj) * OUTv + o];
}

// ---------------- K1: row/col/diag contractions, direction-split --------------
// bx < Nv : col-dir n=bx: rs[n,c] = (1/N) sum_i x[i,n,c]; dgx[n]; obj0 atomics
// bx >= Nv: row-dir n=bx-Nv: cs[n,c] = (1/N) sum_j x[n,j,c]
__global__ __launch_bounds__(256) void k_contract1(const float* __restrict__ x) {
    int bx = blockIdx.x, b = blockIdx.y;
    int t = threadIdx.x, c4 = t & 7, sub = t >> 3;   // 32 subs x 8 float4-cols
    const float4* xb4 = (const float4*)(x + (size_t)b * Nv * Nv * Cv);
    __shared__ float red[32][36];
    float4 acc = {0.f,0.f,0.f,0.f};
    const float invN = 1.0f / Nv;
    if (bx < Nv) {
        int n = bx;
        for (int i = sub; i < Nv; i += 32) {
            float4 v = xb4[((size_t)i * Nv + n) * 8 + c4];
            acc.x += v.x; acc.y += v.y; acc.z += v.z; acc.w += v.w;
        }
        red[sub][c4*4+0] = acc.x; red[sub][c4*4+1] = acc.y;
        red[sub][c4*4+2] = acc.z; red[sub][c4*4+3] = acc.w;
        __syncthreads();
        if (t < 32) {
            float s = 0.f;
            #pragma unroll
            for (int k = 0; k < 32; k++) s += red[k][t];
            s *= invN;
            g_rs[(b * Nv + n) * Cv + t] = s;
            atomicAdd(&g_obj0[b * 64 + t], s * invN);          // rcs partial
        }
        if (t < 8) {
            float4 v = xb4[((size_t)n * Nv + n) * 8 + t];
            ((float4*)g_dgx)[(b * Nv + n) * 8 + t] = v;
            atomicAdd(&g_obj0[b * 64 + 32 + t*4 + 0], v.x * invN);  // ds partial
            atomicAdd(&g_obj0[b * 64 + 32 + t*4 + 1], v.y * invN);
            atomicAdd(&g_obj0[b * 64 + 32 + t*4 + 2], v.z * invN);
            atomicAdd(&g_obj0[b * 64 + 32 + t*4 + 3], v.w * invN);
        }
    } else {
        int n = bx - Nv;
        for (int j = sub; j < Nv; j += 32) {
            float4 v = xb4[((size_t)n * Nv + j) * 8 + c4];
            acc.x += v.x; acc.y += v.y; acc.z += v.z; acc.w += v.w;
        }
        red[sub][c4*4+0] = acc.x; red[sub][c4*4+1] = acc.y;
        red[sub][c4*4+2] = acc.z; red[sub][c4*4+3] = acc.w;
        __syncthreads();
        if (t < 32) {
            float s = 0.f;
            #pragma unroll
            for (int k = 0; k < 32; k++) s += red[k][t];
            g_cs[(b * Nv + n) * Cv + t] = s * invN;
        }
    }
}

// ---------------- K2: neighborhood linear + sigmoid (16 blocks) ---------------
__global__ __launch_bounds__(256) void k_neighb(const float* __restrict__ w1,
                                                const float* __restrict__ b1,
                                                const float* __restrict__ w0,
                                                const float* __restrict__ b0) {
    int ng = blockIdx.x, b = blockIdx.y;
    int t = threadIdx.x;
    __shared__ float obj0[64], t0nb[4];
    if (t < 64) obj0[t] = g_obj0[b * 64 + t];
    __syncthreads();
    if (t < 4) {
        float v = b0[t];
        for (int k = 0; k < 64; k++) v += obj0[k] * w0[k * Mv + t];
        t0nb[t] = v;
    }
    int n = ng * 64 + (t >> 2), part = t & 3;
    float node[4] = {0.f, 0.f, 0.f, 0.f};
    const float* rsr = g_rs  + (size_t)(b * Nv + n) * Cv;
    const float* csr = g_cs  + (size_t)(b * Nv + n) * Cv;
    const float* dgr = g_dgx + (size_t)(b * Nv + n) * Cv;
    #pragma unroll
    for (int q = 0; q < 8; q++) {
        int cc = part * 8 + q;
        float r = rsr[cc], s = csr[cc], d = dgr[cc];
        #pragma unroll
        for (int m = 0; m < 4; m++)
            node[m] += r * w1[cc * Mv + m] + s * w1[(Cv + cc) * Mv + m]
                     + d * w1[(2 * Cv + cc) * Mv + m];
    }
    __shared__ float red[256][4];
    #pragma unroll
    for (int m = 0; m < 4; m++) red[t][m] = node[m];
    __syncthreads();
    if (part == 0) {
        float4 o4;
        #pragma unroll
        for (int m = 0; m < 4; m++) {
            float v = t0nb[m] + b1[m]
                    + red[t][m] + red[t+1][m] + red[t+2][m] + red[t+3][m];
            ((float*)&o4)[m] = 1.0f / (1.0f + expf(-v));
        }
        ((float4*)g_nb)[b * Nv + n] = o4;
    }
}

// ---------------- K3: nb-weighted sums, direction-split ----------------
__global__ __launch_bounds__(256) void k_wsum(const float* __restrict__ x) {
    int bx = blockIdx.x, b = blockIdx.y;
    int t = threadIdx.x, c4 = t & 7, sub = t >> 3;
    __shared__ __align__(16) float4 nbl[Nv];
    if (t < Nv) nbl[t] = ((const float4*)(g_nb + (size_t)b * Nv * Mv))[t];
    __syncthreads();
    const float4* xb4 = (const float4*)(x + (size_t)b * Nv * Nv * Cv);
    float4 a[4];
    #pragma unroll
    for (int m = 0; m < 4; m++) a[m] = {0.f,0.f,0.f,0.f};
    __shared__ float red[32][132];
    if (bx < Nv) {
        int n = bx;
        for (int i = sub; i < Nv; i += 32) {
            float4 v = xb4[((size_t)i * Nv + n) * 8 + c4];
            float4 nv = nbl[i];
            a[0].x += nv.x*v.x; a[0].y += nv.x*v.y; a[0].z += nv.x*v.z; a[0].w += nv.x*v.w;
            a[1].x += nv.y*v.x; a[1].y += nv.y*v.y; a[1].z += nv.y*v.z; a[1].w += nv.y*v.w;
            a[2].x += nv.z*v.x; a[2].y += nv.z*v.y; a[2].z += nv.z*v.z; a[2].w += nv.z*v.w;
            a[3].x += nv.w*v.x; a[3].y += nv.w*v.y; a[3].z += nv.w*v.z; a[3].w += nv.w*v.w;
        }
        #pragma unroll
        for (int m = 0; m < 4; m++) {
            red[sub][m*32 + c4*4+0] = a[m].x; red[sub][m*32 + c4*4+1] = a[m].y;
            red[sub][m*32 + c4*4+2] = a[m].z; red[sub][m*32 + c4*4+3] = a[m].w;
        }
        __syncthreads();
        if (t < 128) {
            float s = 0.f;
            #pragma unroll
            for (int k = 0; k < 32; k++) s += red[k][t];
            g_S1[(size_t)(b * Nv + n) * MCv + t] = s;
            int m = t >> 5, c = t & 31;
            float nv = ((const float*)&nbl[n])[m];
            atomicAdd(&g_rcs2[b * MCv + t], nv * s);
            atomicAdd(&g_ds2 [b * MCv + t], nv * nv * g_dgx[(b * Nv + n) * Cv + c]);
        }
    } else {
        int n = bx - Nv;
        for (int j = sub; j < Nv; j += 32) {
            float4 v = xb4[((size_t)n * Nv + j) * 8 + c4];
            float4 nv = nbl[j];
            a[0].x += nv.x*v.x; a[0].y += nv.x*v.y; a[0].z += nv.x*v.z; a[0].w += nv.x*v.w;
            a[1].x += nv.y*v.x; a[1].y += nv.y*v.y; a[1].z += nv.y*v.z; a[1].w += nv.y*v.w;
            a[2].x += nv.z*v.x; a[2].y += nv.z*v.y; a[2].z += nv.z*v.z; a[2].w += nv.z*v.w;
            a[3].x += nv.w*v.x; a[3].y += nv.w*v.y; a[3].z += nv.w*v.z; a[3].w += nv.w*v.w;
        }
        #pragma unroll
        for (int m = 0; m < 4; m++) {
            red[sub][m*32 + c4*4+0] = a[m].x; red[sub][m*32 + c4*4+1] = a[m].y;
            red[sub][m*32 + c4*4+2] = a[m].z; red[sub][m*32 + c4*4+3] = a[m].w;
        }
        __syncthreads();
        if (t < 128) {
            float s = 0.f;
            #pragma unroll
            for (int k = 0; k < 32; k++) s += red[k][t];
            g_S2[(size_t)(b * Nv + n) * MCv + t] = s;
        }
    }
}

// ---------------- K4: per-column additive term (t0 fused in) ----------------
__global__ __launch_bounds__(256) void k_add(const float* __restrict__ w1d,
                                             const float* __restrict__ b1d,
                                             const float* __restrict__ b2d,
                                             const float* __restrict__ w0d,
                                             const float* __restrict__ b0d) {
    int b = blockIdx.y, n = blockIdx.x;
    int t = threadIdx.x, o = t & 63, ks = t >> 6;   // ks = wave = m / k-slice
    __shared__ float red[4][64];
    const float invN = 1.0f / Nv;
    const float invN2 = 1.0f / ((float)Nv * Nv);
    float acc = 0.f;
    // t0 slice: k in [ks*32, ks*32+32)
    #pragma unroll 8
    for (int c = 0; c < 32; c++) {
        int k = ks * 32 + c;
        float rc = g_rcs2[b * MCv + k] * invN2;
        float dv = g_ds2 [b * MCv + k] * invN;
        acc += rc * w0d[(size_t)k * OUTv + o] + dv * w0d[(size_t)(MCv + k) * OUTv + o];
    }
    // obj1d slice for mc in [ks*32, ks*32+32)
    float nv = g_nb[(b * Nv + n) * Mv + ks];
    float f = nv * invN, d2 = nv * nv;
    const float* S1r = g_S1 + (size_t)(b * Nv + n) * MCv + ks * 32;
    const float* S2r = g_S2 + (size_t)(b * Nv + n) * MCv + ks * 32;
    const float* dgr = g_dgx + (size_t)(b * Nv + n) * Cv;
    #pragma unroll 8
    for (int c = 0; c < 32; c++) {
        int mc = ks * 32 + c;
        acc += f * S1r[c] * w1d[(size_t)mc * OUTv + o]
             + f * S2r[c] * w1d[(size_t)(MCv + mc) * OUTv + o]
             + d2 * dgr[c] * w1d[(size_t)(2 * MCv + mc) * OUTv + o];
    }
    red[ks][o] = acc;
    __syncthreads();
    if (t < 64) {
        float v = red[0][t] + red[1][t] + red[2][t] + red[3][t]
                + b1d[t] + b2d[t] + b0d[t];
        g_addv[(size_t)(b * Nv + n) * OUTv + t] = v;
    }
}

// ---------------- K5: main term via MFMA f16, i-tiled ----------------
#define XPAD 40
__global__ __launch_bounds__(256) void k_main(const float* __restrict__ x,
                                              float* __restrict__ out) {
    int jt = blockIdx.x, ib = blockIdx.y, b = blockIdx.z;
    int j0 = jt * 128, i0 = ib * ITILE;
    int t = threadIdx.x;
    int lane = t & 63, w = t >> 6;
    int rowA = lane & 15, quad = lane >> 4;

    __shared__ __align__(16) _Float16 Wl[8 * 4 * 64 * 8];   // 32 KB
    __shared__ __align__(16) _Float16 Xt[128 * XPAD];        // 10 KB
    __shared__ __align__(16) _Float16 Xb[128 * XPAD];        // 10 KB

    {   // W fragments once per block
        const float4* src = (const float4*)g_wfrag;
        float4* dst = (float4*)Wl;
        #pragma unroll
        for (int r = 0; r < 8; r++) dst[r * 256 + t] = src[r * 256 + t];
    }
    int jl1 = w * 32 + rowA, jl2 = jl1 + 16;
    // addv tile in registers, reused for all i
    float av[2][4][4];
    #pragma unroll
    for (int js = 0; js < 2; js++) {
        int jb = j0 + w * 32 + js * 16 + quad * 4;
        #pragma unroll
        for (int q = 0; q < 4; q++)
            #pragma unroll
            for (int r = 0; r < 4; r++)
                av[js][q][r] = g_addv[(size_t)(b * Nv + jb + r) * OUTv + q * 16 + rowA];
    }
    float4 nj1 = ((const float4*)g_nb)[b * Nv + j0 + jl1];
    float4 nj2 = ((const float4*)g_nb)[b * Nv + j0 + jl2];
    const float4* x4 = (const float4*)x;
    const h8* Wf = (const h8*)Wl;

    for (int ii = 0; ii < ITILE; ii++) {
        int i = i0 + ii;
        // stage Xt/Xb for this i
        #pragma unroll
        for (int r = 0; r < 4; r++) {
            int idx = r * 256 + t;
            int j = idx >> 3, c4 = idx & 7;
            float4 v = x4[((size_t)(b * Nv + i) * Nv + j0 + j) * 8 + c4];
            h4 hv; hv[0] = (_Float16)v.x; hv[1] = (_Float16)v.y;
            hv[2] = (_Float16)v.z; hv[3] = (_Float16)v.w;
            *(h4*)&Xt[j * XPAD + c4 * 4] = hv;
            float4 u = x4[((size_t)(b * Nv + j0 + j) * Nv + i) * 8 + c4];
            h4 hu; hu[0] = (_Float16)u.x; hu[1] = (_Float16)u.y;
            hu[2] = (_Float16)u.z; hu[3] = (_Float16)u.w;
            *(h4*)&Xb[j * XPAD + c4 * 4] = hu;
        }
        float4 ni = ((const float4*)g_nb)[b * Nv + i];
        _Float16 e1h[4], e2h[4];
        #pragma unroll
        for (int m = 0; m < 4; m++) {
            e1h[m] = (_Float16)(((const float*)&ni)[m] * ((const float*)&nj1)[m]);
            e2h[m] = (_Float16)(((const float*)&ni)[m] * ((const float*)&nj2)[m]);
        }
        __syncthreads();

        f4 acc[2][4];
        #pragma unroll
        for (int js = 0; js < 2; js++)
            #pragma unroll
            for (int q = 0; q < 4; q++) acc[js][q] = {0.f, 0.f, 0.f, 0.f};

        #pragma unroll
        for (int part = 0; part < 2; part++) {
            const _Float16* X = part ? Xb : Xt;
            h8 xv1 = *(const h8*)&X[jl1 * XPAD + quad * 8];
            h8 xv2 = *(const h8*)&X[jl2 * XPAD + quad * 8];
            #pragma unroll
            for (int m = 0; m < 4; m++) {
                h8 a1 = xv1 * e1h[m];
                h8 a2 = xv2 * e2h[m];
                int s = part * 4 + m;
                #pragma unroll
                for (int q = 0; q < 4; q++) {
                    h8 bf = Wf[(s * 4 + q) * 64 + lane];
                    acc[0][q] = __builtin_amdgcn_mfma_f32_16x16x32_f16(a1, bf, acc[0][q], 0, 0, 0);
                    acc[1][q] = __builtin_amdgcn_mfma_f32_16x16x32_f16(a2, bf, acc[1][q], 0, 0, 0);
                }
            }
        }
        // epilogue
        #pragma unroll
        for (int js = 0; js < 2; js++) {
            int jbase = j0 + w * 32 + js * 16 + quad * 4;
            #pragma unroll
            for (int q = 0; q < 4; q++) {
                int o = q * 16 + rowA;
                #pragma unroll
                for (int r = 0; r < 4; r++) {
                    int j = jbase + r;
                    float v = acc[js][q][r] + av[js][q][r];
                    __builtin_nontemporal_store(v,
                        &out[(((size_t)(b * Nv + i)) * Nv + j) * OUTv + o]);
                }
            }
        }
        __syncthreads();   // protect LDS reuse for next i
    }
}

extern "C" void kernel_launch(void* const* d_in, const int* in_sizes, int n_in,
                              void* d_out, int out_size, void* d_ws, size_t ws_size,
                              hipStream_t stream) {
    const float* x     = (const float*)d_in[0];
    const float* w1_nb = (const float*)d_in[1];
    const float* b1_nb = (const float*)d_in[2];
    const float* w0_nb = (const float*)d_in[3];
    const float* b0_nb = (const float*)d_in[4];
    const float* w2d   = (const float*)d_in[5];
    const float* b2d   = (const float*)d_in[6];
    const float* w1d   = (const float*)d_in[7];
    const float* b1d   = (const float*)d_in[8];
    const float* w0d   = (const float*)d_in[9];
    const float* b0d   = (const float*)d_in[10];
    float* out = (float*)d_out;
    (void)d_ws; (void)ws_size;

    hipLaunchKernelGGL(k_wpackz, dim3(9), dim3(256), 0, stream, w2d);
    hipLaunchKernelGGL(k_contract1, dim3(2 * Nv, Bv), dim3(256), 0, stream, x);
    hipLaunchKernelGGL(k_neighb, dim3(Nv / 64, Bv), dim3(256), 0, stream,
                       w1_nb, b1_nb, w0_nb, b0_nb);
    hipLaunchKernelGGL(k_wsum, dim3(2 * Nv, Bv), dim3(256), 0, stream, x);
    hipLaunchKernelGGL(k_add, dim3(Nv, Bv), dim3(256), 0, stream,
                       w1d, b1d, b2d, w0d, b0d);
    hipLaunchKernelGGL(k_main, dim3(2, Nv / ITILE, Bv), dim3(256), 0, stream, x, out);
}